// Round 2
// baseline (196.612 us; speedup 1.0000x reference)
//
#include <hip/hip_runtime.h>

typedef float    f32x4  __attribute__((ext_vector_type(4)));
typedef __bf16   bf16x8 __attribute__((ext_vector_type(8)));
typedef unsigned short u16;
typedef unsigned short u16x8 __attribute__((ext_vector_type(8)));
typedef int      i32x4  __attribute__((ext_vector_type(4)));

#define NN   8192
#define FIN  512
#define FOUT 64
#define LOG2E 1.4426950408889634f

#if __has_builtin(__builtin_amdgcn_exp2f)
#define EXP2F(x) __builtin_amdgcn_exp2f(x)
#else
#define EXP2F(x) exp2f(x)
#endif

__device__ __forceinline__ u16 f2bf(float f) {          // f32 -> bf16 RNE
    unsigned int u = __float_as_uint(f);
    u += 0x7FFFu + ((u >> 16) & 1u);
    return (u16)(u >> 16);
}
__device__ __forceinline__ float bf2f(u16 b) {
    return __uint_as_float(((unsigned int)b) << 16);
}

// ---------------------------------------------------------------------------
// K0: W (512x64 f32) -> WT_hi/WT_lo (64x512 bf16, transposed hi/lo split)
// ---------------------------------------------------------------------------
__global__ __launch_bounds__(256) void k_wt(const float* __restrict__ W,
                                            u16* __restrict__ wt_hi,
                                            u16* __restrict__ wt_lo) {
    int t = blockIdx.x * 256 + threadIdx.x;   // 0..32767
    int k = t >> 6, c = t & 63;
    float w = W[t];                            // W[k*64+c]
    u16 h = f2bf(w);
    wt_hi[c * FIN + k] = h;
    wt_lo[c * FIN + k] = f2bf(w - bf2f(h));
}

// ---------------------------------------------------------------------------
// K1: z = input @ W (3-term bf16 MFMA split), s1p/s2p from f32 accumulators.
// grid 512 x 128thr: block = one 16-row m-tile, 2 waves K-split (8 ks each).
// ---------------------------------------------------------------------------
__global__ __launch_bounds__(128) void k_zgemm(
        const float* __restrict__ in, const u16* __restrict__ wt_hi,
        const u16* __restrict__ wt_lo, const float* __restrict__ a,
        float* __restrict__ z, float* __restrict__ s1p, float* __restrict__ s2p)
{
    __shared__ f32x4 xch[4][64];
    const int wv = threadIdx.x >> 6;
    const int l  = threadIdx.x & 63;
    const int lr = l & 15, lk = l >> 4;
    const int row_base = blockIdx.x * 16;

    f32x4 acc[4] = {};
    const float* inrow = in + (size_t)(row_base + lr) * FIN;

    for (int ks = wv * 8; ks < wv * 8 + 8; ++ks) {
        const int k0 = ks * 32 + lk * 8;
        const f32x4 v0 = *(const f32x4*)(inrow + k0);
        const f32x4 v1 = *(const f32x4*)(inrow + k0 + 4);
        u16x8 hv, lv;
#pragma unroll
        for (int i = 0; i < 4; ++i) {
            u16 h = f2bf(v0[i]); hv[i] = h; lv[i] = f2bf(v0[i] - bf2f(h));
        }
#pragma unroll
        for (int i = 0; i < 4; ++i) {
            u16 h = f2bf(v1[i]); hv[4 + i] = h; lv[4 + i] = f2bf(v1[i] - bf2f(h));
        }
        const bf16x8 ahi = __builtin_bit_cast(bf16x8, hv);
        const bf16x8 alo = __builtin_bit_cast(bf16x8, lv);
#pragma unroll
        for (int nt = 0; nt < 4; ++nt) {
            const int wrow = nt * 16 + lr;
            const bf16x8 bh = __builtin_bit_cast(bf16x8, *(const u16x8*)(wt_hi + (size_t)wrow * FIN + k0));
            const bf16x8 bl = __builtin_bit_cast(bf16x8, *(const u16x8*)(wt_lo + (size_t)wrow * FIN + k0));
            acc[nt] = __builtin_amdgcn_mfma_f32_16x16x32_bf16(ahi, bh, acc[nt], 0, 0, 0);
            acc[nt] = __builtin_amdgcn_mfma_f32_16x16x32_bf16(alo, bh, acc[nt], 0, 0, 0);
            acc[nt] = __builtin_amdgcn_mfma_f32_16x16x32_bf16(ahi, bl, acc[nt], 0, 0, 0);
        }
    }

    if (wv == 1) {
#pragma unroll
        for (int nt = 0; nt < 4; ++nt) xch[nt][l] = acc[nt];
    }
    __syncthreads();
    if (wv == 1) return;
#pragma unroll
    for (int nt = 0; nt < 4; ++nt) acc[nt] += xch[nt][l];

    // store z (f32)
#pragma unroll
    for (int nt = 0; nt < 4; ++nt)
#pragma unroll
        for (int r = 0; r < 4; ++r)
            z[(size_t)(row_base + lk * 4 + r) * FOUT + nt * 16 + lr] = acc[nt][r];

    // s1/s2 from exact accumulators
    float a1c[4], a2c[4];
#pragma unroll
    for (int nt = 0; nt < 4; ++nt) {
        a1c[nt] = a[nt * 16 + lr];
        a2c[nt] = a[64 + nt * 16 + lr];
    }
#pragma unroll
    for (int r = 0; r < 4; ++r) {
        float s1 = 0.f, s2 = 0.f;
#pragma unroll
        for (int nt = 0; nt < 4; ++nt) {
            s1 += acc[nt][r] * a1c[nt];
            s2 += acc[nt][r] * a2c[nt];
        }
#pragma unroll
        for (int m = 1; m <= 8; m <<= 1) {
            s1 += __shfl_xor(s1, m, 64);
            s2 += __shfl_xor(s2, m, 64);
        }
        if (lr == 0) {
            s1p[row_base + lk * 4 + r] = s1 * LOG2E;
            s2p[row_base + lk * 4 + r] = s2 * LOG2E;
        }
    }
}

// ---------------------------------------------------------------------------
// K2: zT_hi/zT_lo (64 x 8192 bf16) from z (8192x64 f32). grid 256 x 128.
// ---------------------------------------------------------------------------
__global__ __launch_bounds__(128) void k_zt(const float* __restrict__ z,
                                            u16* __restrict__ zt_hi,
                                            u16* __restrict__ zt_lo) {
    const int t = threadIdx.x;
    const int c = t & 63, jq = t >> 6;            // jq 0..1
    const int j0 = blockIdx.x * 32 + jq * 16;
    u16x8 h0{}, h1{}, l0{}, l1{};
#pragma unroll
    for (int i = 0; i < 8; ++i) {
        float v = z[(size_t)(j0 + i) * FOUT + c];
        u16 h = f2bf(v); h0[i] = h; l0[i] = f2bf(v - bf2f(h));
    }
#pragma unroll
    for (int i = 0; i < 8; ++i) {
        float v = z[(size_t)(j0 + 8 + i) * FOUT + c];
        u16 h = f2bf(v); h1[i] = h; l1[i] = f2bf(v - bf2f(h));
    }
    *(u16x8*)(zt_hi + (size_t)c * NN + j0)     = h0;
    *(u16x8*)(zt_hi + (size_t)c * NN + j0 + 8) = h1;
    *(u16x8*)(zt_lo + (size_t)c * NN + j0)     = l0;
    *(u16x8*)(zt_lo + (size_t)c * NN + j0 + 8) = l1;
}

// ---------------------------------------------------------------------------
// K3: fused masked-softmax attention + PV.
// 512 blocks x 256 thr (4 waves). Block = 16 rows. Wave wv owns k-slices
// {2wv, 2wv+1} of each 256-j tile: it computes w THERE (== its own MFMA
// A-fragment) and consumes it directly from registers.
// -> NO LDS, NO barriers in the main loop. adj prefetched 2 tiles deep into
// named register sets; per-tile load order [zt oldest | adj/s2 newest] keeps
// the zt vmcnt wait counted (never drains the fresh adj HBM loads).
// ---------------------------------------------------------------------------
__global__ __launch_bounds__(256, 2) void k_attn(
        const int* __restrict__ adj, const u16* __restrict__ zt_hi,
        const u16* __restrict__ zt_lo, const float* __restrict__ s1p,
        const float* __restrict__ s2p, const float* __restrict__ bias,
        float* __restrict__ out)
{
    __shared__ float apart[4][16][64];   // 16 KiB (epilogue only)
    __shared__ float dpart[256];         // 1 KiB

    const int t  = threadIdx.x;
    const int wv = t >> 6, l = t & 63;
    const int lr = l & 15, lk = l >> 4;
    const int row0 = blockIdx.x * 16;
    const int koff = wv * 64 + lk * 8;   // wave's k-offset within a 256-tile

    const float s1r = s1p[row0 + lr];
    const int*   arow  = adj + (size_t)(row0 + lr) * NN + koff;
    const float* s2row = s2p + koff;
    const size_t zo[4] = {
        (size_t)(lr)      * NN + (size_t)koff,
        (size_t)(lr + 16) * NN + (size_t)koff,
        (size_t)(lr + 32) * NN + (size_t)koff,
        (size_t)(lr + 48) * NN + (size_t)koff };

    f32x4 acc[4] = {};
    float d = 0.f;

    auto loadset = [&](i32x4* P, f32x4* S, int jn) {
        P[0] = __builtin_nontemporal_load((const i32x4*)(arow + jn));
        P[1] = __builtin_nontemporal_load((const i32x4*)(arow + jn + 4));
        P[2] = __builtin_nontemporal_load((const i32x4*)(arow + jn + 32));
        P[3] = __builtin_nontemporal_load((const i32x4*)(arow + jn + 36));
        S[0] = *(const f32x4*)(s2row + jn);
        S[1] = *(const f32x4*)(s2row + jn + 4);
        S[2] = *(const f32x4*)(s2row + jn + 32);
        S[3] = *(const f32x4*)(s2row + jn + 36);
    };

    auto phaseA = [&](const i32x4& P0, const i32x4& P1,
                      const f32x4& S0, const f32x4& S1) -> bf16x8 {
        bf16x8 wf;
#pragma unroll
        for (int i = 0; i < 8; ++i) {
            const int   av = (i < 4) ? P0[i] : P1[i - 4];
            const float sv = (i < 4) ? S0[i] : S1[i - 4];
            const float y  = s1r + sv;
            const float u  = fmaxf(y, 0.2f * y);
            float w = EXP2F(u);
            w = (av != 0) ? w : 0.0f;
            const __bf16 wb = (__bf16)w;          // RNE (v_cvt_pk_bf16_f32)
            wf[i] = wb;
            d += (float)wb;                        // denom from SAME bf16 weights
        }
        return wf;
    };

    auto body = [&](int jn, i32x4* P, f32x4* S, bool reload) {
        const bf16x8 wf0 = phaseA(P[0], P[1], S[0], S[1]);
        const bf16x8 wf1 = phaseA(P[2], P[3], S[2], S[3]);

        u16x8 zh[2][4], zl[2][4];
#pragma unroll
        for (int s = 0; s < 2; ++s)
#pragma unroll
            for (int nt = 0; nt < 4; ++nt) {
                zh[s][nt] = *(const u16x8*)(zt_hi + zo[nt] + jn + s * 32);
                zl[s][nt] = *(const u16x8*)(zt_lo + zo[nt] + jn + s * 32);
            }

        if (reload) loadset(P, S, jn + 512);       // adj/s2 for tile jt+2 (newest in queue)

#pragma unroll
        for (int s = 0; s < 2; ++s) {
            const bf16x8 A = (s == 0) ? wf0 : wf1;
#pragma unroll
            for (int nt = 0; nt < 4; ++nt) {
                acc[nt] = __builtin_amdgcn_mfma_f32_16x16x32_bf16(A, __builtin_bit_cast(bf16x8, zh[s][nt]), acc[nt], 0, 0, 0);
                acc[nt] = __builtin_amdgcn_mfma_f32_16x16x32_bf16(A, __builtin_bit_cast(bf16x8, zl[s][nt]), acc[nt], 0, 0, 0);
            }
        }
    };

    i32x4 PA[4], PB[4];
    f32x4 SA[4], SB[4];
    loadset(PA, SA, 0);
    loadset(PB, SB, 256);

    for (int jt = 0; jt < 30; jt += 2) {           // hand-peeled 2x: static reg sets
        body(jt * 256,       PA, SA, true);
        body(jt * 256 + 256, PB, SB, true);
    }
    body(30 * 256, PA, SA, false);
    body(31 * 256, PB, SB, false);

    // ---------------- epilogue: cross-wave k-reduction --------------------
    dpart[t] = d;
#pragma unroll
    for (int nt = 0; nt < 4; ++nt)
#pragma unroll
        for (int r = 0; r < 4; ++r)
            apart[wv][lk * 4 + r][nt * 16 + lr] = acc[nt][r];
    __syncthreads();

    {
        const int r  = t >> 4;            // 0..15
        const int c0 = (t & 15) * 4;
        float den = 0.f;
#pragma unroll
        for (int q = 0; q < 16; ++q)
            den += dpart[(q >> 2) * 64 + (q & 3) * 16 + r];
        f32x4 val = {};
#pragma unroll
        for (int q = 0; q < 4; ++q)
            val += *(const f32x4*)&apart[q][r][c0];
        const f32x4 bv = *(const f32x4*)(bias + c0);
        const float dinv = 1.0f / den;
        const f32x4 o = val * dinv + bv;
        *(f32x4*)(out + (size_t)(row0 + r) * FOUT + c0) = o;
    }
}

// ---------------------------------------------------------------------------
extern "C" void kernel_launch(void* const* d_in, const int* in_sizes, int n_in,
                              void* d_out, int out_size, void* d_ws, size_t ws_size,
                              hipStream_t stream) {
    const float* input = (const float*)d_in[0];
    const int*   adj   = (const int*)d_in[1];
    const float* W     = (const float*)d_in[2];
    const float* a     = (const float*)d_in[3];
    const float* bias  = (const float*)d_in[4];
    float* out = (float*)d_out;

    char* ws = (char*)d_ws;
    u16*   wt_hi = (u16*)ws;   ws += FIN * FOUT * sizeof(u16);
    u16*   wt_lo = (u16*)ws;   ws += FIN * FOUT * sizeof(u16);
    float* z     = (float*)ws; ws += (size_t)NN * FOUT * sizeof(float);
    float* s1p   = (float*)ws; ws += NN * sizeof(float);
    float* s2p   = (float*)ws; ws += NN * sizeof(float);
    u16*   zt_hi = (u16*)ws;   ws += (size_t)NN * FOUT * sizeof(u16);
    u16*   zt_lo = (u16*)ws;   ws += (size_t)NN * FOUT * sizeof(u16);

    k_wt   <<<dim3(128), dim3(256), 0, stream>>>(W, wt_hi, wt_lo);
    k_zgemm<<<dim3(512), dim3(128), 0, stream>>>(input, wt_hi, wt_lo, a, z, s1p, s2p);
    k_zt   <<<dim3(256), dim3(128), 0, stream>>>(z, zt_hi, zt_lo);
    k_attn <<<dim3(512), dim3(256), 0, stream>>>(adj, zt_hi, zt_lo, s1p, s2p, bias, out);
}

// Round 3
// 105.393 us; speedup vs baseline: 1.8655x; 1.8655x over previous
//
#include <hip/hip_runtime.h>

typedef float    f32x4  __attribute__((ext_vector_type(4)));
typedef __bf16   bf16x8 __attribute__((ext_vector_type(8)));
typedef unsigned short u16;
typedef unsigned short u16x8 __attribute__((ext_vector_type(8)));
typedef int      i32x4  __attribute__((ext_vector_type(4)));

#define NN   8192
#define FIN  512
#define FOUT 64
#define LOG2E 1.4426950408889634f

#if __has_builtin(__builtin_amdgcn_exp2f)
#define EXP2F(x) __builtin_amdgcn_exp2f(x)
#else
#define EXP2F(x) exp2f(x)
#endif

__device__ __forceinline__ u16 f2bf(float f) {          // f32 -> bf16 RNE
    unsigned int u = __float_as_uint(f);
    u += 0x7FFFu + ((u >> 16) & 1u);
    return (u16)(u >> 16);
}
__device__ __forceinline__ float bf2f(u16 b) {
    return __uint_as_float(((unsigned int)b) << 16);
}

// ---------------------------------------------------------------------------
// K0: W (512x64 f32) -> WT_hi/WT_lo (64x512 bf16, transposed hi/lo split)
// ---------------------------------------------------------------------------
__global__ __launch_bounds__(256) void k_wt(const float* __restrict__ W,
                                            u16* __restrict__ wt_hi,
                                            u16* __restrict__ wt_lo) {
    int t = blockIdx.x * 256 + threadIdx.x;   // 0..32767
    int k = t >> 6, c = t & 63;
    float w = W[t];                            // W[k*64+c]
    u16 h = f2bf(w);
    wt_hi[c * FIN + k] = h;
    wt_lo[c * FIN + k] = f2bf(w - bf2f(h));
}

// ---------------------------------------------------------------------------
// K1: z = input @ W (3-term bf16 MFMA split ~ f32-exact), then:
//   - zt_hi (64 x 8192 bf16, transposed) stored directly from accumulators
//   - s1p = (z@a1)*log2e, s2p = (z@a2)*log2e from f32 accumulators
// grid 512 x 128thr: block = one 16-row m-tile, 2 waves K-split.
// ---------------------------------------------------------------------------
__global__ __launch_bounds__(128) void k_zgemm(
        const float* __restrict__ in, const u16* __restrict__ wt_hi,
        const u16* __restrict__ wt_lo, const float* __restrict__ a,
        u16* __restrict__ zt_hi, float* __restrict__ s1p, float* __restrict__ s2p)
{
    __shared__ f32x4 xch[4][64];
    const int wv = threadIdx.x >> 6;
    const int l  = threadIdx.x & 63;
    const int lr = l & 15, lk = l >> 4;
    const int row_base = blockIdx.x * 16;

    f32x4 acc[4] = {};
    const float* inrow = in + (size_t)(row_base + lr) * FIN;

    for (int ks = wv * 8; ks < wv * 8 + 8; ++ks) {
        const int k0 = ks * 32 + lk * 8;
        const f32x4 v0 = *(const f32x4*)(inrow + k0);
        const f32x4 v1 = *(const f32x4*)(inrow + k0 + 4);
        u16x8 hv, lv;
#pragma unroll
        for (int i = 0; i < 4; ++i) {
            u16 h = f2bf(v0[i]); hv[i] = h; lv[i] = f2bf(v0[i] - bf2f(h));
        }
#pragma unroll
        for (int i = 0; i < 4; ++i) {
            u16 h = f2bf(v1[i]); hv[4 + i] = h; lv[4 + i] = f2bf(v1[i] - bf2f(h));
        }
        const bf16x8 ahi = __builtin_bit_cast(bf16x8, hv);
        const bf16x8 alo = __builtin_bit_cast(bf16x8, lv);
#pragma unroll
        for (int nt = 0; nt < 4; ++nt) {
            const int wrow = nt * 16 + lr;
            const bf16x8 bh = __builtin_bit_cast(bf16x8, *(const u16x8*)(wt_hi + (size_t)wrow * FIN + k0));
            const bf16x8 bl = __builtin_bit_cast(bf16x8, *(const u16x8*)(wt_lo + (size_t)wrow * FIN + k0));
            acc[nt] = __builtin_amdgcn_mfma_f32_16x16x32_bf16(ahi, bh, acc[nt], 0, 0, 0);
            acc[nt] = __builtin_amdgcn_mfma_f32_16x16x32_bf16(alo, bh, acc[nt], 0, 0, 0);
            acc[nt] = __builtin_amdgcn_mfma_f32_16x16x32_bf16(ahi, bl, acc[nt], 0, 0, 0);
        }
    }

    if (wv == 1) {
#pragma unroll
        for (int nt = 0; nt < 4; ++nt) xch[nt][l] = acc[nt];
    }
    __syncthreads();
    if (wv == 1) return;
#pragma unroll
    for (int nt = 0; nt < 4; ++nt) acc[nt] += xch[nt][l];

    // store zt_hi (bf16, transposed): zt[c][j]
#pragma unroll
    for (int nt = 0; nt < 4; ++nt)
#pragma unroll
        for (int r = 0; r < 4; ++r)
            zt_hi[(size_t)(nt * 16 + lr) * NN + row_base + lk * 4 + r] = f2bf(acc[nt][r]);

    // s1/s2 from exact accumulators
    float a1c[4], a2c[4];
#pragma unroll
    for (int nt = 0; nt < 4; ++nt) {
        a1c[nt] = a[nt * 16 + lr];
        a2c[nt] = a[64 + nt * 16 + lr];
    }
#pragma unroll
    for (int r = 0; r < 4; ++r) {
        float s1 = 0.f, s2 = 0.f;
#pragma unroll
        for (int nt = 0; nt < 4; ++nt) {
            s1 += acc[nt][r] * a1c[nt];
            s2 += acc[nt][r] * a2c[nt];
        }
#pragma unroll
        for (int m = 1; m <= 8; m <<= 1) {
            s1 += __shfl_xor(s1, m, 64);
            s2 += __shfl_xor(s2, m, 64);
        }
        if (lr == 0) {
            s1p[row_base + lk * 4 + r] = s1 * LOG2E;
            s2p[row_base + lk * 4 + r] = s2 * LOG2E;
        }
    }
}

// ---------------------------------------------------------------------------
// K3: fused masked-softmax attention + PV.
// 256 blocks x 512 thr (8 waves). Block = 32 rows (2 MFMA row-groups).
// Wave wv owns j-slice [wv*32, wv*32+32) of each 256-j tile: it computes w
// there (== its own MFMA A-fragment) and consumes it from registers.
// No LDS / barriers in the main loop. Pipeline per body N:
//   [issue zt(N+1)] SB(0) [phaseA(N)] [issue adj/s2(N+2)] [MFMA(N)]
// vmcnt FIFO => zt waits are counted, adj gets ~2 bodies of flight.
// All state in NAMED registers (no address-taken arrays -> no scratch).
// ---------------------------------------------------------------------------
#define LOADZ(Z0, Z1, Z2, Z3, jn) do {                                        \
    Z0 = *(const u16x8*)(zp0 + (jn));                                         \
    Z1 = *(const u16x8*)(zp1 + (jn));                                         \
    Z2 = *(const u16x8*)(zp2 + (jn));                                         \
    Z3 = *(const u16x8*)(zp3 + (jn)); } while (0)

#define LOADP(P00, P01, P10, P11, S0, S1, jn) do {                            \
    P00 = __builtin_nontemporal_load((const i32x4*)(ar0 + (jn)));             \
    P01 = __builtin_nontemporal_load((const i32x4*)(ar0 + (jn) + 4));         \
    P10 = __builtin_nontemporal_load((const i32x4*)(ar1 + (jn)));             \
    P11 = __builtin_nontemporal_load((const i32x4*)(ar1 + (jn) + 4));         \
    S0  = *(const f32x4*)(s2r + (jn));                                        \
    S1  = *(const f32x4*)(s2r + (jn) + 4); } while (0)

#define PHA(WF, P0, P1, SS0, SS1, S1R, DD) do {                               \
    _Pragma("unroll")                                                         \
    for (int i = 0; i < 4; ++i) {                                             \
        const float y = (S1R) + SS0[i];                                       \
        float w = EXP2F(fmaxf(y, 0.2f * y));                                  \
        w = (P0[i] != 0) ? w : 0.0f;                                          \
        const __bf16 wb = (__bf16)w;                                          \
        WF[i] = wb; DD += (float)wb; }                                        \
    _Pragma("unroll")                                                         \
    for (int i = 0; i < 4; ++i) {                                             \
        const float y = (S1R) + SS1[i];                                       \
        float w = EXP2F(fmaxf(y, 0.2f * y));                                  \
        w = (P1[i] != 0) ? w : 0.0f;                                          \
        const __bf16 wb = (__bf16)w;                                          \
        WF[4 + i] = wb; DD += (float)wb; } } while (0)

#define MFMA8(WF0, WF1, Z0, Z1, Z2, Z3) do {                                  \
    acc00 = __builtin_amdgcn_mfma_f32_16x16x32_bf16(WF0, __builtin_bit_cast(bf16x8, Z0), acc00, 0, 0, 0); \
    acc01 = __builtin_amdgcn_mfma_f32_16x16x32_bf16(WF0, __builtin_bit_cast(bf16x8, Z1), acc01, 0, 0, 0); \
    acc02 = __builtin_amdgcn_mfma_f32_16x16x32_bf16(WF0, __builtin_bit_cast(bf16x8, Z2), acc02, 0, 0, 0); \
    acc03 = __builtin_amdgcn_mfma_f32_16x16x32_bf16(WF0, __builtin_bit_cast(bf16x8, Z3), acc03, 0, 0, 0); \
    acc10 = __builtin_amdgcn_mfma_f32_16x16x32_bf16(WF1, __builtin_bit_cast(bf16x8, Z0), acc10, 0, 0, 0); \
    acc11 = __builtin_amdgcn_mfma_f32_16x16x32_bf16(WF1, __builtin_bit_cast(bf16x8, Z1), acc11, 0, 0, 0); \
    acc12 = __builtin_amdgcn_mfma_f32_16x16x32_bf16(WF1, __builtin_bit_cast(bf16x8, Z2), acc12, 0, 0, 0); \
    acc13 = __builtin_amdgcn_mfma_f32_16x16x32_bf16(WF1, __builtin_bit_cast(bf16x8, Z3), acc13, 0, 0, 0); } while (0)

#define BODY(CZ0, CZ1, CZ2, CZ3, NZ0, NZ1, NZ2, NZ3,                          \
             P00, P01, P10, P11, S0, S1, jn, DO_Z, DO_P) do {                 \
    if (DO_Z) LOADZ(NZ0, NZ1, NZ2, NZ3, (jn) + 256);                          \
    __builtin_amdgcn_sched_barrier(0);                                        \
    bf16x8 wf0, wf1;                                                          \
    PHA(wf0, P00, P01, S0, S1, s1r0, d0);                                     \
    PHA(wf1, P10, P11, S0, S1, s1r1, d1);                                     \
    if (DO_P) LOADP(P00, P01, P10, P11, S0, S1, (jn) + 512);                  \
    MFMA8(wf0, wf1, CZ0, CZ1, CZ2, CZ3); } while (0)

__global__ __launch_bounds__(512, 2) void k_attn(
        const int* __restrict__ adj, const u16* __restrict__ zt_hi,
        const float* __restrict__ s1p, const float* __restrict__ s2p,
        const float* __restrict__ bias, float* __restrict__ out)
{
    __shared__ float apart[8][32][64];   // 64 KiB (epilogue only)
    __shared__ float dpart[8][4][32];    // 4 KiB

    const int t  = threadIdx.x;
    const int wv = t >> 6, l = t & 63;
    const int lr = l & 15, lk = l >> 4;
    const int row0 = blockIdx.x * 32;
    const int jb = wv * 32 + lk * 8;     // wave+lane j offset within 256-tile

    const float s1r0 = s1p[row0 + lr];
    const float s1r1 = s1p[row0 + 16 + lr];
    const int*   ar0 = adj + (size_t)(row0 + lr) * NN + jb;
    const int*   ar1 = ar0 + (size_t)16 * NN;
    const float* s2r = s2p + jb;
    const u16*   zp0 = zt_hi + (size_t)(lr)      * NN + jb;
    const u16*   zp1 = zt_hi + (size_t)(lr + 16) * NN + jb;
    const u16*   zp2 = zt_hi + (size_t)(lr + 32) * NN + jb;
    const u16*   zp3 = zt_hi + (size_t)(lr + 48) * NN + jb;

    f32x4 acc00{}, acc01{}, acc02{}, acc03{};
    f32x4 acc10{}, acc11{}, acc12{}, acc13{};
    float d0 = 0.f, d1 = 0.f;

    u16x8 zU0, zU1, zU2, zU3, zV0, zV1, zV2, zV3;
    i32x4 pA00, pA01, pA10, pA11, pB00, pB01, pB10, pB11;
    f32x4 sA0, sA1, sB0, sB1;

    LOADZ(zU0, zU1, zU2, zU3, 0);
    LOADP(pA00, pA01, pA10, pA11, sA0, sA1, 0);
    LOADP(pB00, pB01, pB10, pB11, sB0, sB1, 256);

    for (int jt = 0; jt < 30; jt += 2) {
        const int jn = jt * 256;
        BODY(zU0, zU1, zU2, zU3, zV0, zV1, zV2, zV3,
             pA00, pA01, pA10, pA11, sA0, sA1, jn, true, true);
        BODY(zV0, zV1, zV2, zV3, zU0, zU1, zU2, zU3,
             pB00, pB01, pB10, pB11, sB0, sB1, jn + 256, true, true);
    }
    BODY(zU0, zU1, zU2, zU3, zV0, zV1, zV2, zV3,
         pA00, pA01, pA10, pA11, sA0, sA1, 30 * 256, true, false);
    BODY(zV0, zV1, zV2, zV3, zU0, zU1, zU2, zU3,
         pB00, pB01, pB10, pB11, sB0, sB1, 31 * 256, false, false);

    // ---------------- epilogue: cross-wave j-slice reduction -----------------
    dpart[wv][lk][lr]      = d0;
    dpart[wv][lk][16 + lr] = d1;
#pragma unroll
    for (int r = 0; r < 4; ++r) {
        apart[wv][lk * 4 + r][ 0 + lr] = acc00[r];
        apart[wv][lk * 4 + r][16 + lr] = acc01[r];
        apart[wv][lk * 4 + r][32 + lr] = acc02[r];
        apart[wv][lk * 4 + r][48 + lr] = acc03[r];
        apart[wv][16 + lk * 4 + r][ 0 + lr] = acc10[r];
        apart[wv][16 + lk * 4 + r][16 + lr] = acc11[r];
        apart[wv][16 + lk * 4 + r][32 + lr] = acc12[r];
        apart[wv][16 + lk * 4 + r][48 + lr] = acc13[r];
    }
    __syncthreads();

    {
        const int r  = t >> 4;           // 0..31
        const int c0 = (t & 15) * 4;
        float den = 0.f;
#pragma unroll
        for (int q = 0; q < 32; ++q)
            den += dpart[q >> 2][q & 3][r];
        f32x4 val = {};
#pragma unroll
        for (int q = 0; q < 8; ++q)
            val += *(const f32x4*)&apart[q][r][c0];
        const f32x4 bv = *(const f32x4*)(bias + c0);
        const f32x4 o = val * (1.0f / den) + bv;
        *(f32x4*)(out + (size_t)(row0 + r) * FOUT + c0) = o;
    }
}

// ---------------------------------------------------------------------------
extern "C" void kernel_launch(void* const* d_in, const int* in_sizes, int n_in,
                              void* d_out, int out_size, void* d_ws, size_t ws_size,
                              hipStream_t stream) {
    const float* input = (const float*)d_in[0];
    const int*   adj   = (const int*)d_in[1];
    const float* W     = (const float*)d_in[2];
    const float* a     = (const float*)d_in[3];
    const float* bias  = (const float*)d_in[4];
    float* out = (float*)d_out;

    char* ws = (char*)d_ws;
    u16*   wt_hi = (u16*)ws;   ws += FIN * FOUT * sizeof(u16);
    u16*   wt_lo = (u16*)ws;   ws += FIN * FOUT * sizeof(u16);
    float* s1p   = (float*)ws; ws += NN * sizeof(float);
    float* s2p   = (float*)ws; ws += NN * sizeof(float);
    u16*   zt_hi = (u16*)ws;   ws += (size_t)NN * FOUT * sizeof(u16);

    k_wt   <<<dim3(128), dim3(256), 0, stream>>>(W, wt_hi, wt_lo);
    k_zgemm<<<dim3(512), dim3(128), 0, stream>>>(input, wt_hi, wt_lo, a, zt_hi, s1p, s2p);
    k_attn <<<dim3(256), dim3(512), 0, stream>>>(adj, zt_hi, s1p, s2p, bias, out);
}